// Round 11
// baseline (82.801 us; speedup 1.0000x reference)
//
#include <hip/hip_runtime.h>

// Problem constants (match reference.py)
#define NB 65536   // trajectories
#define NT 512     // time points (NT-1 steps)

typedef float f32x2 __attribute__((ext_vector_type(2)));
typedef float f32x4 __attribute__((ext_vector_type(4)));

// 1 trajectory per thread (1 wave/SIMD, fixed TLP). Lone-wave wall tracks the
// serial rcp spine: den -> v_rcp -> rb -> den'. This round shortens the spine
// algebraically (bitwise-neutral in exact math, ~1ulp rounding shift):
//   den_{i+1} = sK + h*k_is = fma(-h, rb_i, fma(hD, ses_i, sK))
// so rb->den is ONE fma (was two: k_is fma then den fma). ses_i is ready ~20cy
// before rb_i, so the bracket is off-chain. Step boundary: carry sK and update
// sK' = fma(h6, sst, sK), so next step's rcp starts parallel to the y-update.
// Uniforms {h2,h6,D,dt,h2D,dtD} staged in LDS (lgkm path -- R8 proved in-loop
// VMEM uniforms serialize against the store stream on vmcnt).
__global__ __launch_bounds__(256) void rk4_biosystem_kernel(
    const float* __restrict__ y0,
    const float* __restrict__ t_eval,
    const float* __restrict__ D_seq,
    const float* __restrict__ K_m_p,
    const float* __restrict__ s_e_p,
    const float* __restrict__ mu_max_p,
    float* __restrict__ out)
{
    __shared__ f32x4 uu[NT][2];  // [t][0]={h2,h6,D,dt} [t][1]={h2D,dtD,0,0}; 16 KiB

    const int tid = threadIdx.x;
    for (int i = tid; i < NT; i += 256) {
        const int j = (i < NT - 1) ? i : (NT - 2);   // pad tail (never used)
        const float dt = t_eval[j + 1] - t_eval[j];  // dt exactly as reference
        const float h2 = dt * 0.5f;
        const float D  = D_seq[j];
        f32x4 a; a.x = h2;      a.y = dt * (1.0f / 6.0f); a.z = D; a.w = dt;
        f32x4 c; c.x = h2 * D;  c.y = dt * D;             c.z = 0; c.w = 0;
        uu[i][0] = a;
        uu[i][1] = c;
    }
    __syncthreads();

    const float K_m    = K_m_p[0];
    const float s_e    = s_e_p[0];
    const float mu_max = mu_max_p[0];

    const int traj = blockIdx.x * 256 + tid;

    const f32x2* __restrict__ y0v = (const f32x2*)y0;
    f32x2 y = y0v[traj];                    // (b, s)
    float b = y.x, s = y.y;

    f32x2* __restrict__ out2 = (f32x2*)out; // out[t][traj][2] as vec2
    out2[traj] = y;                         // row 0 = y0
    f32x2* __restrict__ op = out2 + traj;   // walking output pointer

    // carried across steps: sK = K_m + s (next den1), ses = s_e - s
    float sK  = K_m + s;
    float ses = s_e - s;

    #pragma unroll 8
    for (int t = 0; t < NT - 1; ++t) {
        const f32x4 u0 = uu[t][0];
        const f32x4 u1 = uu[t][1];
        const float h2 = u0.x, h6 = u0.y, D = u0.z, dt = u0.w;
        const float h2D = u1.x, dtD = u1.y;

        // ---- stage 1 ----
        const float inv1 = __builtin_amdgcn_rcpf(sK);
        const float num1 = (mu_max * s) * b;
        const float rb1  = num1 * inv1;
        const float brk2 = __builtin_fmaf(h2D, ses, sK);   // off-chain
        const float den2 = __builtin_fmaf(-h2, rb1, brk2); // rb1 -> den2: 1 fma
        const float inv2 = __builtin_amdgcn_rcpf(den2);
        const float k1b  = __builtin_fmaf(-D, b, rb1);
        const float k1s  = __builtin_fmaf(D, ses, -rb1);

        // ---- stage 2 ----
        const float bb2  = __builtin_fmaf(h2, k1b, b);
        const float ss2  = __builtin_fmaf(h2, k1s, s);
        const float ses2 = s_e - ss2;
        const float num2 = (mu_max * ss2) * bb2;
        const float rb2  = num2 * inv2;
        const float brk3 = __builtin_fmaf(h2D, ses2, sK);
        const float den3 = __builtin_fmaf(-h2, rb2, brk3);
        const float inv3 = __builtin_amdgcn_rcpf(den3);
        const float k2b  = __builtin_fmaf(-D, bb2, rb2);
        const float k2s  = __builtin_fmaf(D, ses2, -rb2);

        // ---- stage 3 ----
        const float bb3  = __builtin_fmaf(h2, k2b, b);
        const float ss3  = __builtin_fmaf(h2, k2s, s);
        const float ses3 = s_e - ss3;
        const float num3 = (mu_max * ss3) * bb3;
        const float rb3  = num3 * inv3;
        const float brk4 = __builtin_fmaf(dtD, ses3, sK);
        const float den4 = __builtin_fmaf(-dt, rb3, brk4);
        const float inv4 = __builtin_amdgcn_rcpf(den4);
        const float k3b  = __builtin_fmaf(-D, bb3, rb3);
        const float k3s  = __builtin_fmaf(D, ses3, -rb3);

        // ---- stage 4 ----
        const float bb4  = __builtin_fmaf(dt, k3b, b);
        const float ss4  = __builtin_fmaf(dt, k3s, s);
        const float ses4 = s_e - ss4;
        const float num4 = (mu_max * ss4) * bb4;
        const float rb4  = num4 * inv4;
        const float k4b  = __builtin_fmaf(-D, bb4, rb4);
        const float k4s  = __builtin_fmaf(D, ses4, -rb4);

        // ---- k-sums + update; sK updated FIRST (next step's rcp operand) ----
        const float sbt = (k1b + k4b) + 2.0f * (k2b + k3b);
        const float sst = (k1s + k4s) + 2.0f * (k2s + k3s);
        sK = __builtin_fmaf(h6, sst, sK);       // next den1, off the y-update
        b  = __builtin_fmaf(h6, sbt, b);
        s  = __builtin_fmaf(h6, sst, s);
        ses = s_e - s;

        op += NB;
        f32x2 v; v.x = b; v.y = s;
        *op = v;
    }
}

extern "C" void kernel_launch(void* const* d_in, const int* in_sizes, int n_in,
                              void* d_out, int out_size, void* d_ws, size_t ws_size,
                              hipStream_t stream) {
    const float* y0     = (const float*)d_in[0];
    const float* t_eval = (const float*)d_in[1];
    const float* D_seq  = (const float*)d_in[2];
    const float* K_m    = (const float*)d_in[3];
    const float* s_e    = (const float*)d_in[4];
    const float* mu_max = (const float*)d_in[5];
    float* out = (float*)d_out;

    dim3 grid(NB / 256);
    dim3 block(256);
    rk4_biosystem_kernel<<<grid, block, 0, stream>>>(y0, t_eval, D_seq, K_m, s_e, mu_max, out);
}

// Round 12
// 62.519 us; speedup vs baseline: 1.3244x; 1.3244x over previous
//
#include <hip/hip_runtime.h>

// Problem constants (match reference.py)
#define NB 65536   // trajectories
#define NT 512     // time points (NT-1 steps)

typedef float f32x2 __attribute__((ext_vector_type(2)));
typedef float f32x4 __attribute__((ext_vector_type(4)));

// R9 restoration — best known structure (62.6 us, 294 cyc/step).
// 1 trajectory per thread: 65536 threads = 1024 waves = 1 wave/SIMD.
// - uniforms on the lgkm path (LDS), ONE ds_read_b128 per step ({h2,h6,D,dt})
//   (R8: in-loop VMEM uniforms serialize vs store stream on vmcnt, -48%;
//    R10/R11: a second b128 read + extra carried state costs ~+85 cyc/step)
// - plain cached stores (L2 absorbs completion; nontemporal was -9%)
// - unroll 8: store-data register rotation gives vmcnt slack
// - rcp off the critical path: rb = (mu_max*s*b) * rcp(K_m+s)
// - den_i = fma(h, k_is, sK) with sK = K_m + s hoisted once per step
__global__ __launch_bounds__(256) void rk4_biosystem_kernel(
    const float* __restrict__ y0,
    const float* __restrict__ t_eval,
    const float* __restrict__ D_seq,
    const float* __restrict__ K_m_p,
    const float* __restrict__ s_e_p,
    const float* __restrict__ mu_max_p,
    float* __restrict__ out)
{
    __shared__ f32x4 u4[NT];   // {h2, h6, D, dt} per step; 8 KiB

    const int tid = threadIdx.x;
    for (int i = tid; i < NT; i += 256) {
        const int j = (i < NT - 1) ? i : (NT - 2);   // pad tail (never used)
        const float dt = t_eval[j + 1] - t_eval[j];  // dt exactly as reference
        f32x4 v;
        v.x = dt * 0.5f;
        v.y = dt * (1.0f / 6.0f);
        v.z = D_seq[j];
        v.w = dt;
        u4[i] = v;
    }
    __syncthreads();

    const float K_m    = K_m_p[0];
    const float s_e    = s_e_p[0];
    const float mu_max = mu_max_p[0];

    const int traj = blockIdx.x * 256 + tid;

    const f32x2* __restrict__ y0v = (const f32x2*)y0;
    f32x2 y = y0v[traj];                    // (b, s)
    float b = y.x, s = y.y;

    f32x2* __restrict__ out2 = (f32x2*)out; // out[t][traj][2] as vec2
    out2[traj] = y;                         // row 0 = y0
    f32x2* __restrict__ op = out2 + traj;   // walking output pointer

    #pragma unroll 8
    for (int t = 0; t < NT - 1; ++t) {
        const f32x4 u = u4[t];
        const float h2 = u.x, h6 = u.y, D = u.z, dt = u.w;

        // once per step, off the stage chain
        const float sK  = K_m + s;          // K_m + s
        const float ses = s_e - s;          // s_e - s
        const float ms  = mu_max * s;

        // stage 1 (ss = s, bb = b)
        const float inv1 = __builtin_amdgcn_rcpf(sK);
        const float num1 = ms * b;
        const float rb1  = num1 * inv1;
        const float k1b  = __builtin_fmaf(-D, b, rb1);
        const float k1s  = __builtin_fmaf(D, ses, -rb1);

        // stage 2
        const float den2 = __builtin_fmaf(h2, k1s, sK);   // K_m + (s + h2*k1s)
        const float inv2 = __builtin_amdgcn_rcpf(den2);
        const float bb2  = __builtin_fmaf(h2, k1b, b);
        const float ss2  = __builtin_fmaf(h2, k1s, s);
        const float num2 = (mu_max * ss2) * bb2;
        const float rb2  = num2 * inv2;
        const float k2b  = __builtin_fmaf(-D, bb2, rb2);
        const float k2s  = __builtin_fmaf(D, s_e - ss2, -rb2);

        // stage 3
        const float den3 = __builtin_fmaf(h2, k2s, sK);
        const float inv3 = __builtin_amdgcn_rcpf(den3);
        const float bb3  = __builtin_fmaf(h2, k2b, b);
        const float ss3  = __builtin_fmaf(h2, k2s, s);
        const float num3 = (mu_max * ss3) * bb3;
        const float rb3  = num3 * inv3;
        const float k3b  = __builtin_fmaf(-D, bb3, rb3);
        const float k3s  = __builtin_fmaf(D, s_e - ss3, -rb3);

        // stage 4 (full dt)
        const float den4 = __builtin_fmaf(dt, k3s, sK);
        const float inv4 = __builtin_amdgcn_rcpf(den4);
        const float bb4  = __builtin_fmaf(dt, k3b, b);
        const float ss4  = __builtin_fmaf(dt, k3s, s);
        const float num4 = (mu_max * ss4) * bb4;
        const float rb4  = num4 * inv4;
        const float k4b  = __builtin_fmaf(-D, bb4, rb4);
        const float k4s  = __builtin_fmaf(D, s_e - ss4, -rb4);

        // parallel reduction trees + update
        const float sb  = (k1b + k4b) + 2.0f * (k2b + k3b);
        const float ss_ = (k1s + k4s) + 2.0f * (k2s + k3s);
        b = __builtin_fmaf(h6, sb, b);
        s = __builtin_fmaf(h6, ss_, s);

        op += NB;
        f32x2 v; v.x = b; v.y = s;
        *op = v;
    }
}

extern "C" void kernel_launch(void* const* d_in, const int* in_sizes, int n_in,
                              void* d_out, int out_size, void* d_ws, size_t ws_size,
                              hipStream_t stream) {
    const float* y0     = (const float*)d_in[0];
    const float* t_eval = (const float*)d_in[1];
    const float* D_seq  = (const float*)d_in[2];
    const float* K_m    = (const float*)d_in[3];
    const float* s_e    = (const float*)d_in[4];
    const float* mu_max = (const float*)d_in[5];
    float* out = (float*)d_out;

    dim3 grid(NB / 256);
    dim3 block(256);
    rk4_biosystem_kernel<<<grid, block, 0, stream>>>(y0, t_eval, D_seq, K_m, s_e, mu_max, out);
}